// Round 5
// baseline (305.678 us; speedup 1.0000x reference)
//
#include <hip/hip_runtime.h>
#include <hip/hip_bf16.h>

// Problem constants
#define B_   8
#define NQ_  2048
#define NKV_ 2048
#define DQ_  512
#define DIN_ 512

using f32x4  = __attribute__((ext_vector_type(4))) float;
using bf16x4 = __attribute__((ext_vector_type(4))) __bf16;
using bf16x8 = __attribute__((ext_vector_type(8))) __bf16;

__device__ __forceinline__ f32x4 mfma16(bf16x8 a, bf16x8 b, f32x4 c) {
  return __builtin_amdgcn_mfma_f32_16x16x32_bf16(a, b, c, 0, 0, 0);
}

// async global->LDS, 16B per lane. LDS dest is wave-uniform base (+lane*16 in HW).
__device__ __forceinline__ void gload_lds16(const __bf16* g, __bf16* l) {
  __builtin_amdgcn_global_load_lds(
      (const __attribute__((address_space(1))) void*)g,
      (__attribute__((address_space(3))) void*)l, 16, 0, 0);
}

// bijective XCD-aware remap (nwg % 8 == 0)
__device__ __forceinline__ int xcd_swz(int bid, int nwg) {
  const int c = nwg >> 3;
  return (bid & 7) * c + (bid >> 3);
}

// ---------------------------------------------------------------------------
// Projection GEMM: C[m,n] = sum_k A[m,k]*B[n,k] + bias[n] (+ key), fp32 in,
// SPLIT bf16 hi/lo out. 3-product split accumulation (hh+hl+lh).
// ---------------------------------------------------------------------------
template<int EPI>
__global__ __launch_bounds__(256, 2)
void proj_gemm(const float* __restrict__ A, const float* __restrict__ Bm,
               __bf16* __restrict__ Ch, __bf16* __restrict__ Cl,
               const float* __restrict__ bias, const float* __restrict__ keyp)
{
  constexpr int PAD = 8;
  __shared__ __bf16 Ah[128][64 + PAD];
  __shared__ __bf16 Al[128][64 + PAD];
  __shared__ __bf16 Bh[128][64 + PAD];
  __shared__ __bf16 Bl[128][64 + PAD];

  const int tid  = threadIdx.x;
  const int lane = tid & 63;
  const int w    = tid >> 6;
  const int wr   = w >> 1;
  const int wc   = w & 1;
  const int brow = blockIdx.y * 128;
  const int bcol = blockIdx.x * 128;

  const float* Ag = A  + (size_t)brow * DQ_;
  const float* Bg = Bm + (size_t)bcol * DQ_;

  f32x4 acc[4][4] = {};

  const int sr = tid >> 4;
  const int sc = (tid & 15) * 4;

  for (int k0 = 0; k0 < DQ_; k0 += 64) {
    __syncthreads();
#pragma unroll
    for (int p = 0; p < 8; ++p) {
      const int r = p * 16 + sr;
      const float4 v = *(const float4*)(Ag + (size_t)r * DQ_ + k0 + sc);
      const float vv[4] = {v.x, v.y, v.z, v.w};
      bf16x4 h, l;
#pragma unroll
      for (int j = 0; j < 4; ++j) {
        const __bf16 hb = (__bf16)vv[j];
        h[j] = hb;
        l[j] = (__bf16)(vv[j] - (float)hb);
      }
      *(bf16x4*)&Ah[r][sc] = h;
      *(bf16x4*)&Al[r][sc] = l;
    }
#pragma unroll
    for (int p = 0; p < 8; ++p) {
      const int r = p * 16 + sr;
      const float4 v = *(const float4*)(Bg + (size_t)r * DQ_ + k0 + sc);
      const float vv[4] = {v.x, v.y, v.z, v.w};
      bf16x4 h, l;
#pragma unroll
      for (int j = 0; j < 4; ++j) {
        const __bf16 hb = (__bf16)vv[j];
        h[j] = hb;
        l[j] = (__bf16)(vv[j] - (float)hb);
      }
      *(bf16x4*)&Bh[r][sc] = h;
      *(bf16x4*)&Bl[r][sc] = l;
    }
    __syncthreads();
#pragma unroll
    for (int kk = 0; kk < 2; ++kk) {
      const int fr = lane & 15;
      const int fc = kk * 32 + (lane >> 4) * 8;
      bf16x8 ah[4], al[4], bh[4], bl[4];
#pragma unroll
      for (int m = 0; m < 4; ++m) {
        ah[m] = *(const bf16x8*)&Ah[wr * 64 + m * 16 + fr][fc];
        al[m] = *(const bf16x8*)&Al[wr * 64 + m * 16 + fr][fc];
      }
#pragma unroll
      for (int n = 0; n < 4; ++n) {
        bh[n] = *(const bf16x8*)&Bh[wc * 64 + n * 16 + fr][fc];
        bl[n] = *(const bf16x8*)&Bl[wc * 64 + n * 16 + fr][fc];
      }
#pragma unroll
      for (int m = 0; m < 4; ++m)
#pragma unroll
        for (int n = 0; n < 4; ++n) {
          acc[m][n] = mfma16(ah[m], bh[n], acc[m][n]);
          acc[m][n] = mfma16(ah[m], bl[n], acc[m][n]);
          acc[m][n] = mfma16(al[m], bh[n], acc[m][n]);
        }
    }
  }

#pragma unroll
  for (int m = 0; m < 4; ++m)
#pragma unroll
    for (int n = 0; n < 4; ++n)
#pragma unroll
      for (int r = 0; r < 4; ++r) {
        const int row_g = brow + wr * 64 + m * 16 + (lane >> 4) * 4 + r;
        const int col_g = bcol + wc * 64 + n * 16 + (lane & 15);
        float vv = acc[m][n][r] + bias[col_g];
        if (EPI == 2) vv += keyp[(size_t)(row_g & (NKV_ - 1)) * DQ_ + col_g];
        const __bf16 h = (__bf16)vv;
        Ch[(size_t)row_g * DQ_ + col_g] = h;
        Cl[(size_t)row_g * DQ_ + col_g] = (__bf16)(vv - (float)h);
      }
}

// ---------------------------------------------------------------------------
// Score GEMM, m201-style 8-phase schedule.
// Virtual-K = 1536 bf16 GEMM: segments [qph.kmh | qph.kml | qpl.kmh].
// 256x256 tile, 512 threads = 8 waves. Per phase ALL waves compute ONE
// 128x128 C-quadrant (wave sub-tile 64x32 = 4m x 2n frags, 16 MFMA).
// K-chunk = 64 virtual-K; half-tile = 128 rows x 64 K = 16 KB = 2 gload_lds
// per thread. LDS: A-ring[2 parity][2 half] + B-ring = 128 KiB.
// Per chunk: 4 quadrant phases Q00,Q01,Q10,Q11; stage order
// [B1(c+1), A1(c+1), A0(c+2), B0(c+2)] at phases 0..3 (each into the slot
// freed by the preceding barrier). ONE counted s_waitcnt vmcnt(4) per chunk
// boundary (retires exactly chunk c+1's 8 loads); vmcnt(0) only at the
// penultimate boundary. No full drains in the main loop.
// ---------------------------------------------------------------------------
__global__ __launch_bounds__(512, 2)
void score_gemm(const __bf16* __restrict__ qph, const __bf16* __restrict__ qpl,
                const __bf16* __restrict__ kmh, const __bf16* __restrict__ kml,
                float* __restrict__ attn)
{
  extern __shared__ __bf16 lds[];
  __bf16* AB = lds;            // A ring: [parity][half][128][64]
  __bf16* BB = lds + 32768;    // B ring: same layout

  const int swz  = xcd_swz(blockIdx.x, gridDim.x);   // 512 blocks
  const int bx   = swz & 7;           // NKV block (256)
  const int by   = (swz >> 3) & 7;    // NQ block (256)
  const int b    = swz >> 6;          // batch

  const int t    = threadIdx.x;       // 0..511
  const int lane = t & 63;
  const int w    = t >> 6;            // 0..7
  const int wr   = w >> 2;            // 0..1 (M within quadrant)
  const int wcn  = w & 3;             // 0..3 (N within quadrant)
  const int brow = by * 256;
  const int bcol = bx * 256;
  const int fr   = lane & 15;
  const int q    = lane >> 4;

  // frag read constants (row&7 == fr&7 for all frag rows)
  const int slotK0 = ((q)     ^ (fr & 7)) * 8;   // kk=0 slot byte-idx (elems)
  const int slotK1 = ((4 + q) ^ (fr & 7)) * 8;   // kk=1
  const int arOff  = (wr * 64 + fr) * 64;        // A row base within half
  const int brOff  = (wcn * 32 + fr) * 64;       // B row base within half

  // staging thread map (identical to proven R3/R4 pattern)
  const int srow = t >> 3;                 // 0..63 within a 64-row issue
  const int sig  = (t & 7) ^ (srow & 7);   // logical slot fetched
  const __bf16* aT0 = qph + ((size_t)b * NQ_  + brow + srow) * DQ_ + sig * 8;
  const __bf16* aT2 = qpl + ((size_t)b * NQ_  + brow + srow) * DQ_ + sig * 8;
  const __bf16* bT0 = kmh + ((size_t)b * NKV_ + bcol + srow) * DQ_ + sig * 8;
  const __bf16* bT1 = kml + ((size_t)b * NKV_ + bcol + srow) * DQ_ + sig * 8;

#define STAGE_A(kc, h) { \
    const __bf16* s_ = ((kc) < 16 ? aT0 : aT2) + ((kc) & 7) * 64 + (size_t)(h) * 128 * DQ_; \
    __bf16* d_ = AB + (((kc) & 1) * 2 + (h)) * 8192 + w * 512; \
    gload_lds16(s_, d_); \
    gload_lds16(s_ + (size_t)64 * DQ_, d_ + 4096); }
#define STAGE_B(kc, h) { \
    const __bf16* s_ = ((((kc) >> 3) == 1) ? bT1 : bT0) + ((kc) & 7) * 64 + (size_t)(h) * 128 * DQ_; \
    __bf16* d_ = BB + (((kc) & 1) * 2 + (h)) * 8192 + w * 512; \
    gload_lds16(s_, d_); \
    gload_lds16(s_ + (size_t)64 * DQ_, d_ + 4096); }

  f32x4 acc[4][4][2] = {};   // [quadrant mh*2+nh][mi][ni]

  // ---- prologue: chunk0 all 4 halves + A0(1), B0(1); wait chunk0 ----
  STAGE_A(0, 0); STAGE_A(0, 1); STAGE_B(0, 0); STAGE_B(0, 1);
  STAGE_A(1, 0); STAGE_B(1, 0);
  asm volatile("s_waitcnt vmcnt(4)\n\ts_barrier" ::: "memory");

#define PHASE(mh, nh, STG) { \
    const __bf16* Ac_ = AB + ((c & 1) * 2 + (mh)) * 8192 + arOff; \
    const __bf16* Bc_ = BB + ((c & 1) * 2 + (nh)) * 8192 + brOff; \
    bf16x8 a0_[4], a1_[4], b0_[2], b1_[2]; \
    _Pragma("unroll") for (int mi = 0; mi < 4; ++mi) { \
      a0_[mi] = *(const bf16x8*)(Ac_ + mi * 1024 + slotK0); \
      a1_[mi] = *(const bf16x8*)(Ac_ + mi * 1024 + slotK1); } \
    _Pragma("unroll") for (int ni = 0; ni < 2; ++ni) { \
      b0_[ni] = *(const bf16x8*)(Bc_ + ni * 1024 + slotK0); \
      b1_[ni] = *(const bf16x8*)(Bc_ + ni * 1024 + slotK1); } \
    STG; \
    asm volatile("s_barrier" ::: "memory"); \
    __builtin_amdgcn_s_setprio(1); \
    _Pragma("unroll") for (int mi = 0; mi < 4; ++mi) \
      _Pragma("unroll") for (int ni = 0; ni < 2; ++ni) { \
        f32x4 c_ = acc[(mh) * 2 + (nh)][mi][ni]; \
        c_ = mfma16(a0_[mi], b0_[ni], c_); \
        c_ = mfma16(a1_[mi], b1_[ni], c_); \
        acc[(mh) * 2 + (nh)][mi][ni] = c_; } \
    __builtin_amdgcn_s_setprio(0); }

  for (int c = 0; c < 24; ++c) {
    // ph0: Q00 reads A0,B0. stage B1(c+1): its slot (parity c+1) free since
    //      end of chunk c-1. consumed at ph(c+1,1).
    PHASE(0, 0, { if (c + 1 < 24) STAGE_B(c + 1, 1); });
    asm volatile("s_barrier" ::: "memory");
    // ph1: Q01 reads A0,B1. stage A1(c+1) (slot free since end chunk c-1).
    PHASE(0, 1, { if (c + 1 < 24) STAGE_A(c + 1, 1); });
    asm volatile("s_barrier" ::: "memory");
    // ph2: Q10 reads A1,B0. stage A0(c+2): overwrites A0(c), whose last read
    //      was ph1 (barrier between).
    PHASE(1, 0, { if (c + 2 < 24) STAGE_A(c + 2, 0); });
    asm volatile("s_barrier" ::: "memory");
    // ph3: Q11 reads A1,B1. stage B0(c+2): overwrites B0(c), last read ph2.
    PHASE(1, 1, { if (c + 2 < 24) STAGE_B(c + 2, 0); });
    // chunk boundary: retire chunk c+1's 8 loads, keep {A0(c+2),B0(c+2)}.
    if (c < 22)       asm volatile("s_waitcnt vmcnt(4)\n\ts_barrier" ::: "memory");
    else if (c == 22) asm volatile("s_waitcnt vmcnt(0)\n\ts_barrier" ::: "memory");
    else              asm volatile("s_barrier" ::: "memory");
  }
#undef PHASE
#undef STAGE_A
#undef STAGE_B

  float* Cg = attn + (size_t)b * NQ_ * NKV_;
#pragma unroll
  for (int mh = 0; mh < 2; ++mh)
#pragma unroll
    for (int nh = 0; nh < 2; ++nh)
#pragma unroll
      for (int mi = 0; mi < 4; ++mi)
#pragma unroll
        for (int ni = 0; ni < 2; ++ni)
#pragma unroll
          for (int r = 0; r < 4; ++r) {
            const int row_g = brow + mh * 128 + wr * 64 + mi * 16 + q * 4 + r;
            const int col_g = bcol + nh * 128 + wcn * 32 + ni * 16 + fr;
            Cg[(size_t)row_g * NKV_ + col_g] = acc[mh * 2 + nh][mi][ni][r];
          }
}

// ---------------------------------------------------------------------------
// PV GEMM: out[b,q,n] = sum_j attnb[b,q,j] * xT[b,n,j]. Both operands bf16,
// staged via global_load_lds with XOR swizzle. BK=64, 32 MFMA/step.
// ---------------------------------------------------------------------------
__global__ __launch_bounds__(256, 2)
void pv_gemm(const __bf16* __restrict__ attnb, const __bf16* __restrict__ xT,
             float* __restrict__ out)
{
  __shared__ __bf16 At[128 * 64];
  __shared__ __bf16 Bt[128 * 64];

  const int swz  = xcd_swz(blockIdx.x, gridDim.x);
  const int bx   = swz & 3;           // DIN block
  const int by   = (swz >> 2) & 15;   // NQ block
  const int b    = swz >> 6;          // batch

  const int t    = threadIdx.x;
  const int lane = t & 63;
  const int w    = t >> 6;
  const int wr   = w >> 1;
  const int wc   = w & 1;
  const int brow = by * 128;   // q rows
  const int bcol = bx * 128;   // din cols

  const int srow  = t >> 3;
  const int sslot = t & 7;
  const int sig   = sslot ^ (srow & 7);
  const __bf16* aG = attnb + ((size_t)b * NQ_ + brow + srow) * NKV_ + sig * 8;
  const __bf16* bG = xT + (size_t)b * DIN_ * NKV_ + (size_t)(bcol + srow) * NKV_ + sig * 8;
  __bf16* aL = At + w * 512;
  __bf16* bL = Bt + w * 512;

  f32x4 acc[4][4] = {};
  const int fr = lane & 15;
  const int q  = lane >> 4;

  for (int ks = 0; ks < NKV_ / 64; ++ks) {
    __syncthreads();
#pragma unroll
    for (int i = 0; i < 4; ++i) {
      gload_lds16(aG + (size_t)i * 32 * NKV_, aL + i * 2048);
      gload_lds16(bG + (size_t)i * 32 * NKV_, bL + i * 2048);
    }
    aG += 64; bG += 64;
    __syncthreads();

#pragma unroll
    for (int kk = 0; kk < 2; ++kk) {
      bf16x8 ah[4], bh[4];
#pragma unroll
      for (int m = 0; m < 4; ++m) {
        const int rt = wr * 64 + m * 16 + fr;
        ah[m] = *(const bf16x8*)&At[rt * 64 + (((kk * 4 + q) ^ (rt & 7)) * 8)];
      }
#pragma unroll
      for (int n = 0; n < 4; ++n) {
        const int rt = wc * 64 + n * 16 + fr;
        bh[n] = *(const bf16x8*)&Bt[rt * 64 + (((kk * 4 + q) ^ (rt & 7)) * 8)];
      }
#pragma unroll
      for (int m = 0; m < 4; ++m)
#pragma unroll
        for (int n = 0; n < 4; ++n)
          acc[m][n] = mfma16(ah[m], bh[n], acc[m][n]);
    }
  }

  float* Cg = out + (size_t)b * NQ_ * DIN_;
#pragma unroll
  for (int m = 0; m < 4; ++m)
#pragma unroll
    for (int n = 0; n < 4; ++n)
#pragma unroll
      for (int r = 0; r < 4; ++r) {
        const int row_g = brow + wr * 64 + m * 16 + q * 4 + r;
        const int col_g = bcol + wc * 64 + n * 16 + fr;
        Cg[(size_t)row_g * DIN_ + col_g] = acc[m][n][r];
      }
}

// ---------------------------------------------------------------------------
// x [B, NKV, DIN] fp32 -> xT [B, DIN, NKV] bf16
// ---------------------------------------------------------------------------
__global__ void transpose_x(const float* __restrict__ x, __bf16* __restrict__ xT)
{
  __shared__ float tile[32][33];
  const int b  = blockIdx.z;
  const int j0 = blockIdx.x * 32;   // NKV index
  const int i0 = blockIdx.y * 32;   // DIN index
  const float* xs = x  + (size_t)b * NKV_ * DIN_;
  __bf16*      xd = xT + (size_t)b * DIN_ * NKV_;
  const int tx = threadIdx.x, ty = threadIdx.y;  // 32 x 8
#pragma unroll
  for (int p = 0; p < 32; p += 8)
    tile[ty + p][tx] = xs[(size_t)(j0 + ty + p) * DIN_ + i0 + tx];
  __syncthreads();
#pragma unroll
  for (int p = 0; p < 32; p += 8)
    xd[(size_t)(i0 + ty + p) * NKV_ + j0 + tx] = (__bf16)tile[tx][ty + p];
}

// ---------------------------------------------------------------------------
// In-place row softmax over attn [rows x 2048]; also writes bf16 copy.
// ---------------------------------------------------------------------------
__global__ void softmax_rows(float* __restrict__ attn, __bf16* __restrict__ attnb)
{
  const int lane = threadIdx.x & 63;
  const int wv   = threadIdx.x >> 6;
  const size_t row = (size_t)blockIdx.x * 4 + wv;
  float*  p  = attn  + row * NKV_;
  __bf16* pb = attnb + row * NKV_;

  float4 v[8];
  float mx = -1e30f;
#pragma unroll
  for (int i = 0; i < 8; ++i) {
    v[i] = *(const float4*)&p[i * 256 + lane * 4];
    mx = fmaxf(mx, fmaxf(fmaxf(v[i].x, v[i].y), fmaxf(v[i].z, v[i].w)));
  }
#pragma unroll
  for (int off = 32; off; off >>= 1) mx = fmaxf(mx, __shfl_xor(mx, off, 64));

  float sum = 0.f;
#pragma unroll
  for (int i = 0; i < 8; ++i) {
    v[i].x = expf(v[i].x - mx);
    v[i].y = expf(v[i].y - mx);
    v[i].z = expf(v[i].z - mx);
    v[i].w = expf(v[i].w - mx);
    sum += v[i].x + v[i].y + v[i].z + v[i].w;
  }
#pragma unroll
  for (int off = 32; off; off >>= 1) sum += __shfl_xor(sum, off, 64);

  const float inv = 1.0f / sum;
#pragma unroll
  for (int i = 0; i < 8; ++i) {
    v[i].x *= inv; v[i].y *= inv; v[i].z *= inv; v[i].w *= inv;
    *(float4*)&p[i * 256 + lane * 4] = v[i];
    bf16x4 hv;
    hv[0] = (__bf16)v[i].x; hv[1] = (__bf16)v[i].y;
    hv[2] = (__bf16)v[i].z; hv[3] = (__bf16)v[i].w;
    *(bf16x4*)&pb[i * 256 + lane * 4] = hv;
  }
}

// ---------------------------------------------------------------------------
extern "C" void kernel_launch(void* const* d_in, const int* in_sizes, int n_in,
                              void* d_out, int out_size, void* d_ws, size_t ws_size,
                              hipStream_t stream)
{
  (void)in_sizes; (void)n_in; (void)out_size; (void)ws_size;
  const float* query  = (const float*)d_in[0];  // [8, 2048, 512]
  const float* key    = (const float*)d_in[1];  // [2048, 512]
  const float* x      = (const float*)d_in[2];  // [8, 2048, 512]
  const float* W_proj = (const float*)d_in[3];  // [512, 512]
  const float* b_proj = (const float*)d_in[4];  // [512]
  const float* W_px   = (const float*)d_in[5];  // [512, 512]
  const float* b_px   = (const float*)d_in[6];  // [512]

  float* out  = (float*)d_out;                          // [8, 2048, 512]
  float* attn = out + (size_t)B_ * NQ_ * DIN_;          // [8, 2048, 2048]

  const size_t PQE = (size_t)B_ * NQ_ * DQ_;            // 8.39M elements
  __bf16* qph = (__bf16*)d_ws;
  __bf16* qpl = qph + PQE;
  __bf16* kmh = qpl + PQE;
  __bf16* kml = kmh + PQE;
  __bf16* xT  = kml + PQE;                              // [8, 512, 2048] bf16
  // after score_gemm, qp/km are dead: reuse their 4*PQE bf16 region (=67.1MB)
  // for the bf16 attn copy (8*2048*2048 = 4*PQE elements exactly).
  __bf16* attnb = qph;

  // allow 128 KiB dynamic LDS for score_gemm (idempotent, capture-safe)
  hipFuncSetAttribute((const void*)score_gemm,
                      hipFuncAttributeMaxDynamicSharedMemorySize, 131072);

  // x^T (bf16) for the PV GEMM B-operand
  transpose_x<<<dim3(NKV_ / 32, DIN_ / 32, B_), dim3(32, 8), 0, stream>>>(x, xT);

  // q_proj = query @ W_proj^T + b_proj  -> split bf16
  proj_gemm<1><<<dim3(DQ_ / 128, (B_ * NQ_) / 128, 1), 256, 0, stream>>>(
      query, W_proj, qph, qpl, b_proj, nullptr);

  // k = x @ W_px^T + b_px + key        -> split bf16
  proj_gemm<2><<<dim3(DQ_ / 128, (B_ * NKV_) / 128, 1), 256, 0, stream>>>(
      x, W_px, kmh, kml, b_px, key);

  // raw scores into attn region of d_out (256^2 tiles, XCD-swizzled)
  score_gemm<<<(NKV_ / 256) * (NQ_ / 256) * B_, 512, 131072, stream>>>(
      qph, qpl, kmh, kml, attn);

  // softmax rows in place + bf16 copy into ws
  softmax_rows<<<(B_ * NQ_) / 4, 256, 0, stream>>>(attn, attnb);

  // out[b] = attn[b] @ x[b]  (1D grid, XCD-swizzled)
  pv_gemm<<<(DIN_ / 128) * (NQ_ / 128) * B_, 256, 0, stream>>>(attnb, xT, out);
}

// Round 6
// 288.988 us; speedup vs baseline: 1.0578x; 1.0578x over previous
//
#include <hip/hip_runtime.h>
#include <hip/hip_bf16.h>

// Problem constants
#define B_   8
#define NQ_  2048
#define NKV_ 2048
#define DQ_  512
#define DIN_ 512

using f32x4  = __attribute__((ext_vector_type(4))) float;
using bf16x4 = __attribute__((ext_vector_type(4))) __bf16;
using bf16x8 = __attribute__((ext_vector_type(8))) __bf16;

__device__ __forceinline__ f32x4 mfma16(bf16x8 a, bf16x8 b, f32x4 c) {
  return __builtin_amdgcn_mfma_f32_16x16x32_bf16(a, b, c, 0, 0, 0);
}

// async global->LDS, 16B per lane. LDS dest is wave-uniform base (+lane*16 in HW).
__device__ __forceinline__ void gload_lds16(const __bf16* g, __bf16* l) {
  __builtin_amdgcn_global_load_lds(
      (const __attribute__((address_space(1))) void*)g,
      (__attribute__((address_space(3))) void*)l, 16, 0, 0);
}

// bijective XCD-aware remap (nwg % 8 == 0)
__device__ __forceinline__ int xcd_swz(int bid, int nwg) {
  const int c = nwg >> 3;
  return (bid & 7) * c + (bid >> 3);
}

// ---------------------------------------------------------------------------
// Projection GEMM: C[m,n] = sum_k A[m,k]*B[n,k] + bias[n] (+ key), fp32 in,
// SPLIT bf16 hi/lo out. 3-product split accumulation (hh+hl+lh).
// ---------------------------------------------------------------------------
template<int EPI>
__global__ __launch_bounds__(256, 2)
void proj_gemm(const float* __restrict__ A, const float* __restrict__ Bm,
               __bf16* __restrict__ Ch, __bf16* __restrict__ Cl,
               const float* __restrict__ bias, const float* __restrict__ keyp)
{
  constexpr int PAD = 8;
  __shared__ __bf16 Ah[128][64 + PAD];
  __shared__ __bf16 Al[128][64 + PAD];
  __shared__ __bf16 Bh[128][64 + PAD];
  __shared__ __bf16 Bl[128][64 + PAD];

  const int tid  = threadIdx.x;
  const int lane = tid & 63;
  const int w    = tid >> 6;
  const int wr   = w >> 1;
  const int wc   = w & 1;
  const int brow = blockIdx.y * 128;
  const int bcol = blockIdx.x * 128;

  const float* Ag = A  + (size_t)brow * DQ_;
  const float* Bg = Bm + (size_t)bcol * DQ_;

  f32x4 acc[4][4] = {};

  const int sr = tid >> 4;
  const int sc = (tid & 15) * 4;

  for (int k0 = 0; k0 < DQ_; k0 += 64) {
    __syncthreads();
#pragma unroll
    for (int p = 0; p < 8; ++p) {
      const int r = p * 16 + sr;
      const float4 v = *(const float4*)(Ag + (size_t)r * DQ_ + k0 + sc);
      const float vv[4] = {v.x, v.y, v.z, v.w};
      bf16x4 h, l;
#pragma unroll
      for (int j = 0; j < 4; ++j) {
        const __bf16 hb = (__bf16)vv[j];
        h[j] = hb;
        l[j] = (__bf16)(vv[j] - (float)hb);
      }
      *(bf16x4*)&Ah[r][sc] = h;
      *(bf16x4*)&Al[r][sc] = l;
    }
#pragma unroll
    for (int p = 0; p < 8; ++p) {
      const int r = p * 16 + sr;
      const float4 v = *(const float4*)(Bg + (size_t)r * DQ_ + k0 + sc);
      const float vv[4] = {v.x, v.y, v.z, v.w};
      bf16x4 h, l;
#pragma unroll
      for (int j = 0; j < 4; ++j) {
        const __bf16 hb = (__bf16)vv[j];
        h[j] = hb;
        l[j] = (__bf16)(vv[j] - (float)hb);
      }
      *(bf16x4*)&Bh[r][sc] = h;
      *(bf16x4*)&Bl[r][sc] = l;
    }
    __syncthreads();
#pragma unroll
    for (int kk = 0; kk < 2; ++kk) {
      const int fr = lane & 15;
      const int fc = kk * 32 + (lane >> 4) * 8;
      bf16x8 ah[4], al[4], bh[4], bl[4];
#pragma unroll
      for (int m = 0; m < 4; ++m) {
        ah[m] = *(const bf16x8*)&Ah[wr * 64 + m * 16 + fr][fc];
        al[m] = *(const bf16x8*)&Al[wr * 64 + m * 16 + fr][fc];
      }
#pragma unroll
      for (int n = 0; n < 4; ++n) {
        bh[n] = *(const bf16x8*)&Bh[wc * 64 + n * 16 + fr][fc];
        bl[n] = *(const bf16x8*)&Bl[wc * 64 + n * 16 + fr][fc];
      }
#pragma unroll
      for (int m = 0; m < 4; ++m)
#pragma unroll
        for (int n = 0; n < 4; ++n) {
          acc[m][n] = mfma16(ah[m], bh[n], acc[m][n]);
          acc[m][n] = mfma16(ah[m], bl[n], acc[m][n]);
          acc[m][n] = mfma16(al[m], bh[n], acc[m][n]);
        }
    }
  }

#pragma unroll
  for (int m = 0; m < 4; ++m)
#pragma unroll
    for (int n = 0; n < 4; ++n)
#pragma unroll
      for (int r = 0; r < 4; ++r) {
        const int row_g = brow + wr * 64 + m * 16 + (lane >> 4) * 4 + r;
        const int col_g = bcol + wc * 64 + n * 16 + (lane & 15);
        float vv = acc[m][n][r] + bias[col_g];
        if (EPI == 2) vv += keyp[(size_t)(row_g & (NKV_ - 1)) * DQ_ + col_g];
        const __bf16 h = (__bf16)vv;
        Ch[(size_t)row_g * DQ_ + col_g] = h;
        Cl[(size_t)row_g * DQ_ + col_g] = (__bf16)(vv - (float)h);
      }
}

// ---------------------------------------------------------------------------
// Score GEMM, 256x256 tile, 512 threads (8 waves, 2M x 4N), deep pipeline.
// Split-aware phases: per phase ONE quadrant (mh,nh), 24 MFMA = 4m x 2n x
// (hh+hl+lh), reads: A-frags reused across ph0/ph1 and ph2/ph3 (snake order
// Q00->Q01->Q11->Q10), so reads/chunk = 12+4+8+4 = 28 per 96 MFMA.
// K-chunk = 32 real K (hi|lo in 64-col rows, XOR slot swizzle).
// LDS ring: [parity][half] per operand, 128 KiB total.
// Stage schedule per chunk c: ph0: A1(c+1), ph1: B0(c+1), ph2: A0(c+2),
// ph3: B1(c+2). ONE s_barrier per phase; counted vmcnt(4) per chunk boundary
// (retires exactly chunk c+1's 8 loads); vmcnt(0) only at c==14.
// ---------------------------------------------------------------------------
__global__ __launch_bounds__(512, 2)
void score_gemm(const __bf16* __restrict__ qph, const __bf16* __restrict__ qpl,
                const __bf16* __restrict__ kmh, const __bf16* __restrict__ kml,
                float* __restrict__ attn)
{
  extern __shared__ __bf16 lds[];
  __bf16* ABuf = lds;            // [parity 2][half 2][128 rows][64] elems
  __bf16* BBuf = lds + 32768;

  const int swz  = xcd_swz(blockIdx.x, gridDim.x);   // 512 blocks
  const int bx   = swz & 7;           // NKV block (256)
  const int by   = (swz >> 3) & 7;    // NQ block (256)
  const int b    = swz >> 6;          // batch

  const int t    = threadIdx.x;       // 0..511
  const int lane = t & 63;
  const int w    = t >> 6;            // 0..7
  const int wr   = w >> 2;            // 0..1 (M)
  const int wcn  = w & 3;             // 0..3 (N)
  const int brow = by * 256;
  const int bcol = bx * 256;
  const int fr   = lane & 15;
  const int q    = lane >> 4;

  // frag-read constants (frag rows have row&7 == fr&7)
  const int slotH = ((q)     ^ (fr & 7)) * 8;
  const int slotL = ((4 + q) ^ (fr & 7)) * 8;
  const int arOff = (wr * 64 + fr) * 64;    // A row base within a half
  const int brOff = (wcn * 32 + fr) * 64;   // B row base within a half

  // staging map (proven R3/R5 pattern)
  const int srow = t >> 3;                  // 0..63
  const int sig  = (t & 7) ^ (srow & 7);    // logical slot fetched
  const __bf16* aGh = qph + ((size_t)b * NQ_  + brow + srow) * DQ_ + (sig & 3) * 8;
  const __bf16* aGl = qpl + ((size_t)b * NQ_  + brow + srow) * DQ_ + (sig & 3) * 8;
  const __bf16* bGh = kmh + ((size_t)b * NKV_ + bcol + srow) * DQ_ + (sig & 3) * 8;
  const __bf16* bGl = kml + ((size_t)b * NKV_ + bcol + srow) * DQ_ + (sig & 3) * 8;

#define STAGE_A(kc, h) do { \
    const __bf16* s_ = (sig < 4 ? aGh : aGl) + (kc) * 32 + (size_t)(h) * 128 * DQ_; \
    __bf16* d_ = ABuf + (((kc) & 1) * 2 + (h)) * 8192 + w * 512; \
    gload_lds16(s_, d_); \
    gload_lds16(s_ + (size_t)64 * DQ_, d_ + 4096); } while (0)
#define STAGE_B(kc, h) do { \
    const __bf16* s_ = (sig < 4 ? bGh : bGl) + (kc) * 32 + (size_t)(h) * 128 * DQ_; \
    __bf16* d_ = BBuf + (((kc) & 1) * 2 + (h)) * 8192 + w * 512; \
    gload_lds16(s_, d_); \
    gload_lds16(s_ + (size_t)64 * DQ_, d_ + 4096); } while (0)

  f32x4 acc[4][4][2] = {};   // [quad = mh*2+nh][mi][ni]

  // prologue: chunk0 (all 4 halves) + A0(1), B1(1); retire chunk0's 8 loads.
  STAGE_A(0, 0); STAGE_B(0, 1); STAGE_A(0, 1); STAGE_B(0, 0);
  STAGE_A(1, 0); STAGE_B(1, 1);
  asm volatile("s_waitcnt vmcnt(4)\n\ts_barrier" ::: "memory");

  for (int c = 0; c < 16; ++c) {
    const int par = (c & 1) * 2;
    bf16x8 ah[4], al[4], bh[2], bl[2];

    // ---- ph0: Q00 (A half0, B half0); stage A1(c+1) ----
    {
      const __bf16* Ab = ABuf + (par + 0) * 8192 + arOff;
      const __bf16* Bb = BBuf + (par + 0) * 8192 + brOff;
#pragma unroll
      for (int mi = 0; mi < 4; ++mi) {
        ah[mi] = *(const bf16x8*)(Ab + mi * 1024 + slotH);
        al[mi] = *(const bf16x8*)(Ab + mi * 1024 + slotL);
      }
#pragma unroll
      for (int ni = 0; ni < 2; ++ni) {
        bh[ni] = *(const bf16x8*)(Bb + ni * 1024 + slotH);
        bl[ni] = *(const bf16x8*)(Bb + ni * 1024 + slotL);
      }
      if (c + 1 < 16) STAGE_A(c + 1, 1);
      __builtin_amdgcn_s_setprio(1);
#pragma unroll
      for (int mi = 0; mi < 4; ++mi)
#pragma unroll
        for (int ni = 0; ni < 2; ++ni) {
          f32x4 cc = acc[0][mi][ni];
          cc = mfma16(ah[mi], bh[ni], cc);
          cc = mfma16(ah[mi], bl[ni], cc);
          cc = mfma16(al[mi], bh[ni], cc);
          acc[0][mi][ni] = cc;
        }
      __builtin_amdgcn_s_setprio(0);
      asm volatile("s_barrier" ::: "memory");
    }

    // ---- ph1: Q01 (A half0 reused, B half1); stage B0(c+1) ----
    {
      const __bf16* Bb = BBuf + (par + 1) * 8192 + brOff;
#pragma unroll
      for (int ni = 0; ni < 2; ++ni) {
        bh[ni] = *(const bf16x8*)(Bb + ni * 1024 + slotH);
        bl[ni] = *(const bf16x8*)(Bb + ni * 1024 + slotL);
      }
      if (c + 1 < 16) STAGE_B(c + 1, 0);
      __builtin_amdgcn_s_setprio(1);
#pragma unroll
      for (int mi = 0; mi < 4; ++mi)
#pragma unroll
        for (int ni = 0; ni < 2; ++ni) {
          f32x4 cc = acc[1][mi][ni];
          cc = mfma16(ah[mi], bh[ni], cc);
          cc = mfma16(ah[mi], bl[ni], cc);
          cc = mfma16(al[mi], bh[ni], cc);
          acc[1][mi][ni] = cc;
        }
      __builtin_amdgcn_s_setprio(0);
      asm volatile("s_barrier" ::: "memory");
    }

    // ---- ph2: Q11 (A half1, B half1 reused); stage A0(c+2) ----
    {
      const __bf16* Ab = ABuf + (par + 1) * 8192 + arOff;
#pragma unroll
      for (int mi = 0; mi < 4; ++mi) {
        ah[mi] = *(const bf16x8*)(Ab + mi * 1024 + slotH);
        al[mi] = *(const bf16x8*)(Ab + mi * 1024 + slotL);
      }
      if (c + 2 < 16) STAGE_A(c + 2, 0);
      __builtin_amdgcn_s_setprio(1);
#pragma unroll
      for (int mi = 0; mi < 4; ++mi)
#pragma unroll
        for (int ni = 0; ni < 2; ++ni) {
          f32x4 cc = acc[3][mi][ni];
          cc = mfma16(ah[mi], bh[ni], cc);
          cc = mfma16(ah[mi], bl[ni], cc);
          cc = mfma16(al[mi], bh[ni], cc);
          acc[3][mi][ni] = cc;
        }
      __builtin_amdgcn_s_setprio(0);
      asm volatile("s_barrier" ::: "memory");
    }

    // ---- ph3: Q10 (A half1 reused, B half0 re-read); stage B1(c+2) ----
    {
      const __bf16* Bb = BBuf + (par + 0) * 8192 + brOff;
#pragma unroll
      for (int ni = 0; ni < 2; ++ni) {
        bh[ni] = *(const bf16x8*)(Bb + ni * 1024 + slotH);
        bl[ni] = *(const bf16x8*)(Bb + ni * 1024 + slotL);
      }
      if (c + 2 < 16) STAGE_B(c + 2, 1);
      __builtin_amdgcn_s_setprio(1);
#pragma unroll
      for (int mi = 0; mi < 4; ++mi)
#pragma unroll
        for (int ni = 0; ni < 2; ++ni) {
          f32x4 cc = acc[2][mi][ni];
          cc = mfma16(ah[mi], bh[ni], cc);
          cc = mfma16(ah[mi], bl[ni], cc);
          cc = mfma16(al[mi], bh[ni], cc);
          acc[2][mi][ni] = cc;
        }
      __builtin_amdgcn_s_setprio(0);
      // chunk boundary: retire chunk c+1's 8 loads; keep c+2's 4 in flight.
      if (c <= 13)      asm volatile("s_waitcnt vmcnt(4)\n\ts_barrier" ::: "memory");
      else if (c == 14) asm volatile("s_waitcnt vmcnt(0)\n\ts_barrier" ::: "memory");
      // c == 15: last chunk, no successor reads — fall through to epilogue.
    }
  }
#undef STAGE_A
#undef STAGE_B

  float* Cg = attn + (size_t)b * NQ_ * NKV_;
#pragma unroll
  for (int mh = 0; mh < 2; ++mh)
#pragma unroll
    for (int nh = 0; nh < 2; ++nh)
#pragma unroll
      for (int mi = 0; mi < 4; ++mi)
#pragma unroll
        for (int ni = 0; ni < 2; ++ni)
#pragma unroll
          for (int r = 0; r < 4; ++r) {
            const int row_g = brow + mh * 128 + wr * 64 + mi * 16 + q * 4 + r;
            const int col_g = bcol + nh * 128 + wcn * 32 + ni * 16 + fr;
            Cg[(size_t)row_g * NKV_ + col_g] = acc[mh * 2 + nh][mi][ni][r];
          }
}

// ---------------------------------------------------------------------------
// PV GEMM: out[b,q,n] = sum_j attnb[b,q,j] * xT[b,n,j]. Both operands bf16,
// staged via global_load_lds with XOR swizzle. BK=64, 32 MFMA/step.
// ---------------------------------------------------------------------------
__global__ __launch_bounds__(256, 2)
void pv_gemm(const __bf16* __restrict__ attnb, const __bf16* __restrict__ xT,
             float* __restrict__ out)
{
  __shared__ __bf16 At[128 * 64];
  __shared__ __bf16 Bt[128 * 64];

  const int swz  = xcd_swz(blockIdx.x, gridDim.x);
  const int bx   = swz & 3;           // DIN block
  const int by   = (swz >> 2) & 15;   // NQ block
  const int b    = swz >> 6;          // batch

  const int t    = threadIdx.x;
  const int lane = t & 63;
  const int w    = t >> 6;
  const int wr   = w >> 1;
  const int wc   = w & 1;
  const int brow = by * 128;   // q rows
  const int bcol = bx * 128;   // din cols

  const int srow  = t >> 3;
  const int sslot = t & 7;
  const int sig   = sslot ^ (srow & 7);
  const __bf16* aG = attnb + ((size_t)b * NQ_ + brow + srow) * NKV_ + sig * 8;
  const __bf16* bG = xT + (size_t)b * DIN_ * NKV_ + (size_t)(bcol + srow) * NKV_ + sig * 8;
  __bf16* aL = At + w * 512;
  __bf16* bL = Bt + w * 512;

  f32x4 acc[4][4] = {};
  const int fr = lane & 15;
  const int q  = lane >> 4;

  for (int ks = 0; ks < NKV_ / 64; ++ks) {
    __syncthreads();
#pragma unroll
    for (int i = 0; i < 4; ++i) {
      gload_lds16(aG + (size_t)i * 32 * NKV_, aL + i * 2048);
      gload_lds16(bG + (size_t)i * 32 * NKV_, bL + i * 2048);
    }
    aG += 64; bG += 64;
    __syncthreads();

#pragma unroll
    for (int kk = 0; kk < 2; ++kk) {
      bf16x8 ah[4], bh[4];
#pragma unroll
      for (int m = 0; m < 4; ++m) {
        const int rt = wr * 64 + m * 16 + fr;
        ah[m] = *(const bf16x8*)&At[rt * 64 + (((kk * 4 + q) ^ (rt & 7)) * 8)];
      }
#pragma unroll
      for (int n = 0; n < 4; ++n) {
        const int rt = wc * 64 + n * 16 + fr;
        bh[n] = *(const bf16x8*)&Bt[rt * 64 + (((kk * 4 + q) ^ (rt & 7)) * 8)];
      }
#pragma unroll
      for (int m = 0; m < 4; ++m)
#pragma unroll
        for (int n = 0; n < 4; ++n)
          acc[m][n] = mfma16(ah[m], bh[n], acc[m][n]);
    }
  }

  float* Cg = out + (size_t)b * NQ_ * DIN_;
#pragma unroll
  for (int m = 0; m < 4; ++m)
#pragma unroll
    for (int n = 0; n < 4; ++n)
#pragma unroll
      for (int r = 0; r < 4; ++r) {
        const int row_g = brow + wr * 64 + m * 16 + q * 4 + r;
        const int col_g = bcol + wc * 64 + n * 16 + fr;
        Cg[(size_t)row_g * DIN_ + col_g] = acc[m][n][r];
      }
}

// ---------------------------------------------------------------------------
// x [B, NKV, DIN] fp32 -> xT [B, DIN, NKV] bf16
// ---------------------------------------------------------------------------
__global__ void transpose_x(const float* __restrict__ x, __bf16* __restrict__ xT)
{
  __shared__ float tile[32][33];
  const int b  = blockIdx.z;
  const int j0 = blockIdx.x * 32;   // NKV index
  const int i0 = blockIdx.y * 32;   // DIN index
  const float* xs = x  + (size_t)b * NKV_ * DIN_;
  __bf16*      xd = xT + (size_t)b * DIN_ * NKV_;
  const int tx = threadIdx.x, ty = threadIdx.y;  // 32 x 8
#pragma unroll
  for (int p = 0; p < 32; p += 8)
    tile[ty + p][tx] = xs[(size_t)(j0 + ty + p) * DIN_ + i0 + tx];
  __syncthreads();
#pragma unroll
  for (int p = 0; p < 32; p += 8)
    xd[(size_t)(i0 + ty + p) * NKV_ + j0 + tx] = (__bf16)tile[tx][ty + p];
}

// ---------------------------------------------------------------------------
// In-place row softmax over attn [rows x 2048]; also writes bf16 copy.
// ---------------------------------------------------------------------------
__global__ void softmax_rows(float* __restrict__ attn, __bf16* __restrict__ attnb)
{
  const int lane = threadIdx.x & 63;
  const int wv   = threadIdx.x >> 6;
  const size_t row = (size_t)blockIdx.x * 4 + wv;
  float*  p  = attn  + row * NKV_;
  __bf16* pb = attnb + row * NKV_;

  float4 v[8];
  float mx = -1e30f;
#pragma unroll
  for (int i = 0; i < 8; ++i) {
    v[i] = *(const float4*)&p[i * 256 + lane * 4];
    mx = fmaxf(mx, fmaxf(fmaxf(v[i].x, v[i].y), fmaxf(v[i].z, v[i].w)));
  }
#pragma unroll
  for (int off = 32; off; off >>= 1) mx = fmaxf(mx, __shfl_xor(mx, off, 64));

  float sum = 0.f;
#pragma unroll
  for (int i = 0; i < 8; ++i) {
    v[i].x = expf(v[i].x - mx);
    v[i].y = expf(v[i].y - mx);
    v[i].z = expf(v[i].z - mx);
    v[i].w = expf(v[i].w - mx);
    sum += v[i].x + v[i].y + v[i].z + v[i].w;
  }
#pragma unroll
  for (int off = 32; off; off >>= 1) sum += __shfl_xor(sum, off, 64);

  const float inv = 1.0f / sum;
#pragma unroll
  for (int i = 0; i < 8; ++i) {
    v[i].x *= inv; v[i].y *= inv; v[i].z *= inv; v[i].w *= inv;
    *(float4*)&p[i * 256 + lane * 4] = v[i];
    bf16x4 hv;
    hv[0] = (__bf16)v[i].x; hv[1] = (__bf16)v[i].y;
    hv[2] = (__bf16)v[i].z; hv[3] = (__bf16)v[i].w;
    *(bf16x4*)&pb[i * 256 + lane * 4] = hv;
  }
}

// ---------------------------------------------------------------------------
extern "C" void kernel_launch(void* const* d_in, const int* in_sizes, int n_in,
                              void* d_out, int out_size, void* d_ws, size_t ws_size,
                              hipStream_t stream)
{
  (void)in_sizes; (void)n_in; (void)out_size; (void)ws_size;
  const float* query  = (const float*)d_in[0];  // [8, 2048, 512]
  const float* key    = (const float*)d_in[1];  // [2048, 512]
  const float* x      = (const float*)d_in[2];  // [8, 2048, 512]
  const float* W_proj = (const float*)d_in[3];  // [512, 512]
  const float* b_proj = (const float*)d_in[4];  // [512]
  const float* W_px   = (const float*)d_in[5];  // [512, 512]
  const float* b_px   = (const float*)d_in[6];  // [512]

  float* out  = (float*)d_out;                          // [8, 2048, 512]
  float* attn = out + (size_t)B_ * NQ_ * DIN_;          // [8, 2048, 2048]

  const size_t PQE = (size_t)B_ * NQ_ * DQ_;            // 8.39M elements
  __bf16* qph = (__bf16*)d_ws;
  __bf16* qpl = qph + PQE;
  __bf16* kmh = qpl + PQE;
  __bf16* kml = kmh + PQE;
  __bf16* xT  = kml + PQE;                              // [8, 512, 2048] bf16
  // after score_gemm, qp/km are dead: reuse their 4*PQE bf16 region (=67.1MB)
  // for the bf16 attn copy (8*2048*2048 = 4*PQE elements exactly).
  __bf16* attnb = qph;

  // allow 128 KiB dynamic LDS for score_gemm (idempotent, capture-safe)
  hipFuncSetAttribute((const void*)score_gemm,
                      hipFuncAttributeMaxDynamicSharedMemorySize, 131072);

  // x^T (bf16) for the PV GEMM B-operand
  transpose_x<<<dim3(NKV_ / 32, DIN_ / 32, B_), dim3(32, 8), 0, stream>>>(x, xT);

  // q_proj = query @ W_proj^T + b_proj  -> split bf16
  proj_gemm<1><<<dim3(DQ_ / 128, (B_ * NQ_) / 128, 1), 256, 0, stream>>>(
      query, W_proj, qph, qpl, b_proj, nullptr);

  // k = x @ W_px^T + b_px + key        -> split bf16
  proj_gemm<2><<<dim3(DQ_ / 128, (B_ * NKV_) / 128, 1), 256, 0, stream>>>(
      x, W_px, kmh, kml, b_px, key);

  // raw scores into attn region of d_out (256^2 tiles, XCD-swizzled)
  score_gemm<<<(NKV_ / 256) * (NQ_ / 256) * B_, 512, 131072, stream>>>(
      qph, qpl, kmh, kml, attn);

  // softmax rows in place + bf16 copy into ws
  softmax_rows<<<(B_ * NQ_) / 4, 256, 0, stream>>>(attn, attnb);

  // out[b] = attn[b] @ x[b]  (1D grid, XCD-swizzled)
  pv_gemm<<<(DIN_ / 128) * (NQ_ / 128) * B_, 256, 0, stream>>>(attnb, xT, out);
}

// Round 7
// 286.980 us; speedup vs baseline: 1.0652x; 1.0070x over previous
//
#include <hip/hip_runtime.h>
#include <hip/hip_bf16.h>

// Problem constants
#define B_   8
#define NQ_  2048
#define NKV_ 2048
#define DQ_  512
#define DIN_ 512

using f32x4  = __attribute__((ext_vector_type(4))) float;
using bf16x4 = __attribute__((ext_vector_type(4))) __bf16;
using bf16x8 = __attribute__((ext_vector_type(8))) __bf16;

__device__ __forceinline__ f32x4 mfma16(bf16x8 a, bf16x8 b, f32x4 c) {
  return __builtin_amdgcn_mfma_f32_16x16x32_bf16(a, b, c, 0, 0, 0);
}

// async global->LDS, 16B per lane. LDS dest is wave-uniform base (+lane*16 in HW).
__device__ __forceinline__ void gload_lds16(const __bf16* g, __bf16* l) {
  __builtin_amdgcn_global_load_lds(
      (const __attribute__((address_space(1))) void*)g,
      (__attribute__((address_space(3))) void*)l, 16, 0, 0);
}

// bijective XCD-aware remap (nwg % 8 == 0)
__device__ __forceinline__ int xcd_swz(int bid, int nwg) {
  const int c = nwg >> 3;
  return (bid & 7) * c + (bid >> 3);
}

// ---------------------------------------------------------------------------
// Projection GEMM: C[m,n] = sum_k A[m,k]*B[n,k] + bias[n] (+ key), fp32 in,
// SPLIT bf16 hi/lo out. 3-product split accumulation (hh+hl+lh).
// T14 issue-early: next chunk's 16 float4 preloaded into regs during compute;
// cvt + LDS write happen after the barrier (load latency hides under MFMA).
// ---------------------------------------------------------------------------
template<int EPI>
__global__ __launch_bounds__(256, 2)
void proj_gemm(const float* __restrict__ A, const float* __restrict__ Bm,
               __bf16* __restrict__ Ch, __bf16* __restrict__ Cl,
               const float* __restrict__ bias, const float* __restrict__ keyp)
{
  constexpr int PAD = 8;
  __shared__ __bf16 Ah[128][64 + PAD];
  __shared__ __bf16 Al[128][64 + PAD];
  __shared__ __bf16 Bh[128][64 + PAD];
  __shared__ __bf16 Bl[128][64 + PAD];

  const int tid  = threadIdx.x;
  const int lane = tid & 63;
  const int w    = tid >> 6;
  const int wr   = w >> 1;
  const int wc   = w & 1;
  const int brow = blockIdx.y * 128;
  const int bcol = blockIdx.x * 128;

  const float* Ag = A  + (size_t)brow * DQ_;
  const float* Bg = Bm + (size_t)bcol * DQ_;

  f32x4 acc[4][4] = {};

  const int sr = tid >> 4;
  const int sc = (tid & 15) * 4;

  float4 pa[8], pb[8];
#pragma unroll
  for (int p = 0; p < 8; ++p) {
    pa[p] = *(const float4*)(Ag + (size_t)(p * 16 + sr) * DQ_ + sc);
    pb[p] = *(const float4*)(Bg + (size_t)(p * 16 + sr) * DQ_ + sc);
  }

  for (int k0 = 0; k0 < DQ_; k0 += 64) {
    __syncthreads();
    // write preloaded chunk k0 into LDS (split hi/lo)
#pragma unroll
    for (int p = 0; p < 8; ++p) {
      const int r = p * 16 + sr;
      const float vva[4] = {pa[p].x, pa[p].y, pa[p].z, pa[p].w};
      const float vvb[4] = {pb[p].x, pb[p].y, pb[p].z, pb[p].w};
      bf16x4 ha, la, hb, lb;
#pragma unroll
      for (int j = 0; j < 4; ++j) {
        const __bf16 hba = (__bf16)vva[j];
        ha[j] = hba; la[j] = (__bf16)(vva[j] - (float)hba);
        const __bf16 hbb = (__bf16)vvb[j];
        hb[j] = hbb; lb[j] = (__bf16)(vvb[j] - (float)hbb);
      }
      *(bf16x4*)&Ah[r][sc] = ha;
      *(bf16x4*)&Al[r][sc] = la;
      *(bf16x4*)&Bh[r][sc] = hb;
      *(bf16x4*)&Bl[r][sc] = lb;
    }
    // issue next chunk's loads (fly during compute below)
    if (k0 + 64 < DQ_) {
#pragma unroll
      for (int p = 0; p < 8; ++p) {
        pa[p] = *(const float4*)(Ag + (size_t)(p * 16 + sr) * DQ_ + k0 + 64 + sc);
        pb[p] = *(const float4*)(Bg + (size_t)(p * 16 + sr) * DQ_ + k0 + 64 + sc);
      }
    }
    __syncthreads();
#pragma unroll
    for (int kk = 0; kk < 2; ++kk) {
      const int fr = lane & 15;
      const int fc = kk * 32 + (lane >> 4) * 8;
      bf16x8 ah[4], al[4], bh[4], bl[4];
#pragma unroll
      for (int m = 0; m < 4; ++m) {
        ah[m] = *(const bf16x8*)&Ah[wr * 64 + m * 16 + fr][fc];
        al[m] = *(const bf16x8*)&Al[wr * 64 + m * 16 + fr][fc];
      }
#pragma unroll
      for (int n = 0; n < 4; ++n) {
        bh[n] = *(const bf16x8*)&Bh[wc * 64 + n * 16 + fr][fc];
        bl[n] = *(const bf16x8*)&Bl[wc * 64 + n * 16 + fr][fc];
      }
#pragma unroll
      for (int m = 0; m < 4; ++m)
#pragma unroll
        for (int n = 0; n < 4; ++n) {
          acc[m][n] = mfma16(ah[m], bh[n], acc[m][n]);
          acc[m][n] = mfma16(ah[m], bl[n], acc[m][n]);
          acc[m][n] = mfma16(al[m], bh[n], acc[m][n]);
        }
    }
  }

#pragma unroll
  for (int m = 0; m < 4; ++m)
#pragma unroll
    for (int n = 0; n < 4; ++n)
#pragma unroll
      for (int r = 0; r < 4; ++r) {
        const int row_g = brow + wr * 64 + m * 16 + (lane >> 4) * 4 + r;
        const int col_g = bcol + wc * 64 + n * 16 + (lane & 15);
        float vv = acc[m][n][r] + bias[col_g];
        if (EPI == 2) vv += keyp[(size_t)(row_g & (NKV_ - 1)) * DQ_ + col_g];
        const __bf16 h = (__bf16)vv;
        Ch[(size_t)row_g * DQ_ + col_g] = h;
        Cl[(size_t)row_g * DQ_ + col_g] = (__bf16)(vv - (float)h);
      }
}

// ---------------------------------------------------------------------------
// Score GEMM, 256x256 tile, 512 threads (8 waves, 2M x 4N), deep pipeline.
// Snake quadrant order Q00->Q01->Q11->Q10 with register reuse: A frags reused
// across ph0/ph1 and ph2/ph3; B half1 frags across ph1/ph2; B half0 frags
// HELD IN REGISTERS from ph0 and reused at ph3 (no re-read): 24 reads/chunk
// for 96 MFMA. Counted vmcnt(4) at chunk boundaries only.
// ---------------------------------------------------------------------------
__global__ __launch_bounds__(512, 2)
void score_gemm(const __bf16* __restrict__ qph, const __bf16* __restrict__ qpl,
                const __bf16* __restrict__ kmh, const __bf16* __restrict__ kml,
                float* __restrict__ attn)
{
  extern __shared__ __bf16 lds[];
  __bf16* ABuf = lds;            // [parity 2][half 2][128 rows][64] elems
  __bf16* BBuf = lds + 32768;

  const int swz  = xcd_swz(blockIdx.x, gridDim.x);   // 512 blocks
  const int bx   = swz & 7;           // NKV block (256)
  const int by   = (swz >> 3) & 7;    // NQ block (256)
  const int b    = swz >> 6;          // batch

  const int t    = threadIdx.x;       // 0..511
  const int lane = t & 63;
  const int w    = t >> 6;            // 0..7
  const int wr   = w >> 2;            // 0..1 (M)
  const int wcn  = w & 3;             // 0..3 (N)
  const int brow = by * 256;
  const int bcol = bx * 256;
  const int fr   = lane & 15;
  const int q    = lane >> 4;

  // frag-read constants (frag rows have row&7 == fr&7)
  const int slotH = ((q)     ^ (fr & 7)) * 8;
  const int slotL = ((4 + q) ^ (fr & 7)) * 8;
  const int arOff = (wr * 64 + fr) * 64;    // A row base within a half
  const int brOff = (wcn * 32 + fr) * 64;   // B row base within a half

  // staging map (proven R3/R5 pattern)
  const int srow = t >> 3;                  // 0..63
  const int sig  = (t & 7) ^ (srow & 7);    // logical slot fetched
  const __bf16* aGh = qph + ((size_t)b * NQ_  + brow + srow) * DQ_ + (sig & 3) * 8;
  const __bf16* aGl = qpl + ((size_t)b * NQ_  + brow + srow) * DQ_ + (sig & 3) * 8;
  const __bf16* bGh = kmh + ((size_t)b * NKV_ + bcol + srow) * DQ_ + (sig & 3) * 8;
  const __bf16* bGl = kml + ((size_t)b * NKV_ + bcol + srow) * DQ_ + (sig & 3) * 8;

#define STAGE_A(kc, h) do { \
    const __bf16* s_ = (sig < 4 ? aGh : aGl) + (kc) * 32 + (size_t)(h) * 128 * DQ_; \
    __bf16* d_ = ABuf + (((kc) & 1) * 2 + (h)) * 8192 + w * 512; \
    gload_lds16(s_, d_); \
    gload_lds16(s_ + (size_t)64 * DQ_, d_ + 4096); } while (0)
#define STAGE_B(kc, h) do { \
    const __bf16* s_ = (sig < 4 ? bGh : bGl) + (kc) * 32 + (size_t)(h) * 128 * DQ_; \
    __bf16* d_ = BBuf + (((kc) & 1) * 2 + (h)) * 8192 + w * 512; \
    gload_lds16(s_, d_); \
    gload_lds16(s_ + (size_t)64 * DQ_, d_ + 4096); } while (0)

  f32x4 acc[4][4][2] = {};   // [quad = mh*2+nh][mi][ni]

  // prologue: chunk0 (all 4 halves) + A0(1), B1(1); retire chunk0's 8 loads.
  STAGE_A(0, 0); STAGE_B(0, 1); STAGE_A(0, 1); STAGE_B(0, 0);
  STAGE_A(1, 0); STAGE_B(1, 1);
  asm volatile("s_waitcnt vmcnt(4)\n\ts_barrier" ::: "memory");

  for (int c = 0; c < 16; ++c) {
    const int par = (c & 1) * 2;
    bf16x8 ah[4], al[4], bh[2], bl[2];
    bf16x8 b0h[2], b0l[2];   // B half0 held ph0 -> ph3

    // ---- ph0: Q00 (A half0, B half0); stage A1(c+1) ----
    {
      const __bf16* Ab = ABuf + (par + 0) * 8192 + arOff;
      const __bf16* Bb = BBuf + (par + 0) * 8192 + brOff;
#pragma unroll
      for (int mi = 0; mi < 4; ++mi) {
        ah[mi] = *(const bf16x8*)(Ab + mi * 1024 + slotH);
        al[mi] = *(const bf16x8*)(Ab + mi * 1024 + slotL);
      }
#pragma unroll
      for (int ni = 0; ni < 2; ++ni) {
        b0h[ni] = *(const bf16x8*)(Bb + ni * 1024 + slotH);
        b0l[ni] = *(const bf16x8*)(Bb + ni * 1024 + slotL);
      }
      if (c + 1 < 16) STAGE_A(c + 1, 1);
      __builtin_amdgcn_s_setprio(1);
#pragma unroll
      for (int mi = 0; mi < 4; ++mi)
#pragma unroll
        for (int ni = 0; ni < 2; ++ni) {
          f32x4 cc = acc[0][mi][ni];
          cc = mfma16(ah[mi], b0h[ni], cc);
          cc = mfma16(ah[mi], b0l[ni], cc);
          cc = mfma16(al[mi], b0h[ni], cc);
          acc[0][mi][ni] = cc;
        }
      __builtin_amdgcn_s_setprio(0);
      asm volatile("s_barrier" ::: "memory");
    }

    // ---- ph1: Q01 (A half0 reused, B half1); stage B0(c+1) ----
    {
      const __bf16* Bb = BBuf + (par + 1) * 8192 + brOff;
#pragma unroll
      for (int ni = 0; ni < 2; ++ni) {
        bh[ni] = *(const bf16x8*)(Bb + ni * 1024 + slotH);
        bl[ni] = *(const bf16x8*)(Bb + ni * 1024 + slotL);
      }
      if (c + 1 < 16) STAGE_B(c + 1, 0);
      __builtin_amdgcn_s_setprio(1);
#pragma unroll
      for (int mi = 0; mi < 4; ++mi)
#pragma unroll
        for (int ni = 0; ni < 2; ++ni) {
          f32x4 cc = acc[1][mi][ni];
          cc = mfma16(ah[mi], bh[ni], cc);
          cc = mfma16(ah[mi], bl[ni], cc);
          cc = mfma16(al[mi], bh[ni], cc);
          acc[1][mi][ni] = cc;
        }
      __builtin_amdgcn_s_setprio(0);
      asm volatile("s_barrier" ::: "memory");
    }

    // ---- ph2: Q11 (A half1, B half1 reused); stage A0(c+2) ----
    {
      const __bf16* Ab = ABuf + (par + 1) * 8192 + arOff;
#pragma unroll
      for (int mi = 0; mi < 4; ++mi) {
        ah[mi] = *(const bf16x8*)(Ab + mi * 1024 + slotH);
        al[mi] = *(const bf16x8*)(Ab + mi * 1024 + slotL);
      }
      if (c + 2 < 16) STAGE_A(c + 2, 0);
      __builtin_amdgcn_s_setprio(1);
#pragma unroll
      for (int mi = 0; mi < 4; ++mi)
#pragma unroll
        for (int ni = 0; ni < 2; ++ni) {
          f32x4 cc = acc[3][mi][ni];
          cc = mfma16(ah[mi], bh[ni], cc);
          cc = mfma16(ah[mi], bl[ni], cc);
          cc = mfma16(al[mi], bh[ni], cc);
          acc[3][mi][ni] = cc;
        }
      __builtin_amdgcn_s_setprio(0);
      asm volatile("s_barrier" ::: "memory");
    }

    // ---- ph3: Q10 (A half1 reused, B half0 FROM REGS); stage B1(c+2) ----
    {
      if (c + 2 < 16) STAGE_B(c + 2, 1);
      __builtin_amdgcn_s_setprio(1);
#pragma unroll
      for (int mi = 0; mi < 4; ++mi)
#pragma unroll
        for (int ni = 0; ni < 2; ++ni) {
          f32x4 cc = acc[2][mi][ni];
          cc = mfma16(ah[mi], b0h[ni], cc);
          cc = mfma16(ah[mi], b0l[ni], cc);
          cc = mfma16(al[mi], b0h[ni], cc);
          acc[2][mi][ni] = cc;
        }
      __builtin_amdgcn_s_setprio(0);
      // chunk boundary: retire chunk c+1's 8 loads; keep c+2's 4 in flight.
      if (c <= 13)      asm volatile("s_waitcnt vmcnt(4)\n\ts_barrier" ::: "memory");
      else if (c == 14) asm volatile("s_waitcnt vmcnt(0)\n\ts_barrier" ::: "memory");
      // c == 15: last chunk, no successor reads — fall through to epilogue.
    }
  }
#undef STAGE_A
#undef STAGE_B

  float* Cg = attn + (size_t)b * NQ_ * NKV_;
#pragma unroll
  for (int mh = 0; mh < 2; ++mh)
#pragma unroll
    for (int nh = 0; nh < 2; ++nh)
#pragma unroll
      for (int mi = 0; mi < 4; ++mi)
#pragma unroll
        for (int ni = 0; ni < 2; ++ni)
#pragma unroll
          for (int r = 0; r < 4; ++r) {
            const int row_g = brow + mh * 128 + wr * 64 + mi * 16 + q * 4 + r;
            const int col_g = bcol + nh * 128 + wcn * 32 + ni * 16 + fr;
            Cg[(size_t)row_g * NKV_ + col_g] = acc[mh * 2 + nh][mi][ni][r];
          }
}

// ---------------------------------------------------------------------------
// PV GEMM: out[b,q,n] = sum_j attnb[b,q,j] * xT[b,n,j]. Both operands bf16,
// double-buffered T3 2-phase: stage chunk ks+1 during compute of ks; single
// counted vmcnt(0) AFTER the MFMA cluster. 64 KB LDS -> 2 blocks/CU.
// ---------------------------------------------------------------------------
__global__ __launch_bounds__(256, 2)
void pv_gemm(const __bf16* __restrict__ attnb, const __bf16* __restrict__ xT,
             float* __restrict__ out)
{
  __shared__ __bf16 At[2][128 * 64];
  __shared__ __bf16 Bt[2][128 * 64];

  const int swz  = xcd_swz(blockIdx.x, gridDim.x);
  const int bx   = swz & 3;           // DIN block
  const int by   = (swz >> 2) & 15;   // NQ block
  const int b    = swz >> 6;          // batch

  const int t    = threadIdx.x;
  const int lane = t & 63;
  const int w    = t >> 6;
  const int wr   = w >> 1;
  const int wc   = w & 1;
  const int brow = by * 128;   // q rows
  const int bcol = bx * 128;   // din cols

  const int srow  = t >> 3;
  const int sslot = t & 7;
  const int sig   = sslot ^ (srow & 7);
  const __bf16* aG = attnb + ((size_t)b * NQ_ + brow + srow) * NKV_ + sig * 8;
  const __bf16* bG = xT + (size_t)b * DIN_ * NKV_ + (size_t)(bcol + srow) * NKV_ + sig * 8;

  f32x4 acc[4][4] = {};
  const int fr = lane & 15;
  const int q  = lane >> 4;

#define PV_STAGE(ks, buf) do { \
    const __bf16* a_ = aG + (size_t)(ks) * 64; \
    const __bf16* b_ = bG + (size_t)(ks) * 64; \
    __bf16* al_ = At[buf] + w * 512; \
    __bf16* bl_ = Bt[buf] + w * 512; \
    _Pragma("unroll") for (int i = 0; i < 4; ++i) { \
      gload_lds16(a_ + (size_t)i * 32 * NKV_, al_ + i * 2048); \
      gload_lds16(b_ + (size_t)i * 32 * NKV_, bl_ + i * 2048); } } while (0)

  // prologue: stage chunk 0, drain, barrier.
  PV_STAGE(0, 0);
  asm volatile("s_waitcnt vmcnt(0)\n\ts_barrier" ::: "memory");

  for (int ks = 0; ks < NKV_ / 64; ++ks) {
    const int cur = ks & 1;
    if (ks + 1 < NKV_ / 64) PV_STAGE(ks + 1, cur ^ 1);

    const __bf16* Ac = At[cur];
    const __bf16* Bc = Bt[cur];
#pragma unroll
    for (int kk = 0; kk < 2; ++kk) {
      bf16x8 ah[4], bh[4];
#pragma unroll
      for (int m = 0; m < 4; ++m) {
        const int rt = wr * 64 + m * 16 + fr;
        ah[m] = *(const bf16x8*)&Ac[rt * 64 + (((kk * 4 + q) ^ (rt & 7)) * 8)];
      }
#pragma unroll
      for (int n = 0; n < 4; ++n) {
        const int rt = wc * 64 + n * 16 + fr;
        bh[n] = *(const bf16x8*)&Bc[rt * 64 + (((kk * 4 + q) ^ (rt & 7)) * 8)];
      }
#pragma unroll
      for (int m = 0; m < 4; ++m)
#pragma unroll
        for (int n = 0; n < 4; ++n)
          acc[m][n] = mfma16(ah[m], bh[n], acc[m][n]);
    }
    // next buffer must be complete before next iteration reads it; loads
    // issued above had the whole read+MFMA cluster to land.
    asm volatile("s_waitcnt vmcnt(0)\n\ts_barrier" ::: "memory");
  }
#undef PV_STAGE

  float* Cg = out + (size_t)b * NQ_ * DIN_;
#pragma unroll
  for (int m = 0; m < 4; ++m)
#pragma unroll
    for (int n = 0; n < 4; ++n)
#pragma unroll
      for (int r = 0; r < 4; ++r) {
        const int row_g = brow + wr * 64 + m * 16 + q * 4 + r;
        const int col_g = bcol + wc * 64 + n * 16 + fr;
        Cg[(size_t)row_g * DIN_ + col_g] = acc[m][n][r];
      }
}

// ---------------------------------------------------------------------------
// x [B, NKV, DIN] fp32 -> xT [B, DIN, NKV] bf16
// ---------------------------------------------------------------------------
__global__ void transpose_x(const float* __restrict__ x, __bf16* __restrict__ xT)
{
  __shared__ float tile[32][33];
  const int b  = blockIdx.z;
  const int j0 = blockIdx.x * 32;   // NKV index
  const int i0 = blockIdx.y * 32;   // DIN index
  const float* xs = x  + (size_t)b * NKV_ * DIN_;
  __bf16*      xd = xT + (size_t)b * DIN_ * NKV_;
  const int tx = threadIdx.x, ty = threadIdx.y;  // 32 x 8
#pragma unroll
  for (int p = 0; p < 32; p += 8)
    tile[ty + p][tx] = xs[(size_t)(j0 + ty + p) * DIN_ + i0 + tx];
  __syncthreads();
#pragma unroll
  for (int p = 0; p < 32; p += 8)
    xd[(size_t)(i0 + ty + p) * NKV_ + j0 + tx] = (__bf16)tile[tx][ty + p];
}

// ---------------------------------------------------------------------------
// In-place row softmax over attn [rows x 2048]; also writes bf16 copy.
// ---------------------------------------------------------------------------
__global__ void softmax_rows(float* __restrict__ attn, __bf16* __restrict__ attnb)
{
  const int lane = threadIdx.x & 63;
  const int wv   = threadIdx.x >> 6;
  const size_t row = (size_t)blockIdx.x * 4 + wv;
  float*  p  = attn  + row * NKV_;
  __bf16* pb = attnb + row * NKV_;

  float4 v[8];
  float mx = -1e30f;
#pragma unroll
  for (int i = 0; i < 8; ++i) {
    v[i] = *(const float4*)&p[i * 256 + lane * 4];
    mx = fmaxf(mx, fmaxf(fmaxf(v[i].x, v[i].y), fmaxf(v[i].z, v[i].w)));
  }
#pragma unroll
  for (int off = 32; off; off >>= 1) mx = fmaxf(mx, __shfl_xor(mx, off, 64));

  float sum = 0.f;
#pragma unroll
  for (int i = 0; i < 8; ++i) {
    v[i].x = expf(v[i].x - mx);
    v[i].y = expf(v[i].y - mx);
    v[i].z = expf(v[i].z - mx);
    v[i].w = expf(v[i].w - mx);
    sum += v[i].x + v[i].y + v[i].z + v[i].w;
  }
#pragma unroll
  for (int off = 32; off; off >>= 1) sum += __shfl_xor(sum, off, 64);

  const float inv = 1.0f / sum;
#pragma unroll
  for (int i = 0; i < 8; ++i) {
    v[i].x *= inv; v[i].y *= inv; v[i].z *= inv; v[i].w *= inv;
    *(float4*)&p[i * 256 + lane * 4] = v[i];
    bf16x4 hv;
    hv[0] = (__bf16)v[i].x; hv[1] = (__bf16)v[i].y;
    hv[2] = (__bf16)v[i].z; hv[3] = (__bf16)v[i].w;
    *(bf16x4*)&pb[i * 256 + lane * 4] = hv;
  }
}

// ---------------------------------------------------------------------------
extern "C" void kernel_launch(void* const* d_in, const int* in_sizes, int n_in,
                              void* d_out, int out_size, void* d_ws, size_t ws_size,
                              hipStream_t stream)
{
  (void)in_sizes; (void)n_in; (void)out_size; (void)ws_size;
  const float* query  = (const float*)d_in[0];  // [8, 2048, 512]
  const float* key    = (const float*)d_in[1];  // [2048, 512]
  const float* x      = (const float*)d_in[2];  // [8, 2048, 512]
  const float* W_proj = (const float*)d_in[3];  // [512, 512]
  const float* b_proj = (const float*)d_in[4];  // [512]
  const float* W_px   = (const float*)d_in[5];  // [512, 512]
  const float* b_px   = (const float*)d_in[6];  // [512]

  float* out  = (float*)d_out;                          // [8, 2048, 512]
  float* attn = out + (size_t)B_ * NQ_ * DIN_;          // [8, 2048, 2048]

  const size_t PQE = (size_t)B_ * NQ_ * DQ_;            // 8.39M elements
  __bf16* qph = (__bf16*)d_ws;
  __bf16* qpl = qph + PQE;
  __bf16* kmh = qpl + PQE;
  __bf16* kml = kmh + PQE;
  __bf16* xT  = kml + PQE;                              // [8, 512, 2048] bf16
  // after score_gemm, qp/km are dead: reuse their 4*PQE bf16 region (=67.1MB)
  // for the bf16 attn copy (8*2048*2048 = 4*PQE elements exactly).
  __bf16* attnb = qph;

  // allow 128 KiB dynamic LDS for score_gemm (idempotent, capture-safe)
  hipFuncSetAttribute((const void*)score_gemm,
                      hipFuncAttributeMaxDynamicSharedMemorySize, 131072);

  // x^T (bf16) for the PV GEMM B-operand
  transpose_x<<<dim3(NKV_ / 32, DIN_ / 32, B_), dim3(32, 8), 0, stream>>>(x, xT);

  // q_proj = query @ W_proj^T + b_proj  -> split bf16
  proj_gemm<1><<<dim3(DQ_ / 128, (B_ * NQ_) / 128, 1), 256, 0, stream>>>(
      query, W_proj, qph, qpl, b_proj, nullptr);

  // k = x @ W_px^T + b_px + key        -> split bf16
  proj_gemm<2><<<dim3(DQ_ / 128, (B_ * NKV_) / 128, 1), 256, 0, stream>>>(
      x, W_px, kmh, kml, b_px, key);

  // raw scores into attn region of d_out (256^2 tiles, XCD-swizzled)
  score_gemm<<<(NKV_ / 256) * (NQ_ / 256) * B_, 512, 131072, stream>>>(
      qph, qpl, kmh, kml, attn);

  // softmax rows in place + bf16 copy into ws
  softmax_rows<<<(B_ * NQ_) / 4, 256, 0, stream>>>(attn, attnb);

  // out[b] = attn[b] @ x[b]  (1D grid, XCD-swizzled)
  pv_gemm<<<(DIN_ / 128) * (NQ_ / 128) * B_, 256, 0, stream>>>(attnb, xT, out);
}